// Round 6
// baseline (7838.434 us; speedup 1.0000x reference)
//
#include <hip/hip_runtime.h>
#include <hip/hip_bf16.h>
#include <hip/hip_fp16.h>

typedef __attribute__((ext_vector_type(8))) short s16x8;
typedef __attribute__((ext_vector_type(8))) _Float16 f16x8;
typedef __attribute__((ext_vector_type(4))) float f32x4;

// ---------------------------------------------------------------------------
// Dequant 8 int4-in-int32 -> 8 fp16 via bit-trick + pk_fma.
// f16(64+q) = 0x5400 | (q<<4);  w = b*s - (64+z)*s
// Scale/zero loaded by caller just before (short live range, no MFMA overlap).
// ---------------------------------------------------------------------------
__device__ __forceinline__ s16x8 dq_compute(int4 q0, int4 q1, float s, float z) {
  __half hs = __float2half(s);
  __half2 s2 = __halves2half2(hs, hs);
  __half hc = __float2half(-(64.f + z) * s);
  __half2 c2 = __halves2half2(hc, hc);
  uint32_t b0 = 0x54005400u + ((uint32_t)q0.x << 4) + ((uint32_t)q0.y << 20);
  uint32_t b1 = 0x54005400u + ((uint32_t)q0.z << 4) + ((uint32_t)q0.w << 20);
  uint32_t b2 = 0x54005400u + ((uint32_t)q1.x << 4) + ((uint32_t)q1.y << 20);
  uint32_t b3 = 0x54005400u + ((uint32_t)q1.z << 4) + ((uint32_t)q1.w << 20);
  union { s16x8 v; __half2 h2[4]; } w;
  w.h2[0] = __hfma2(*(__half2*)&b0, s2, c2);
  w.h2[1] = __hfma2(*(__half2*)&b1, s2, c2);
  w.h2[2] = __hfma2(*(__half2*)&b2, s2, c2);
  w.h2[3] = __hfma2(*(__half2*)&b3, s2, c2);
  return w.v;
}

// bijective XCD swizzle (m204): hardware id -> logical workgroup id.
// Consecutive logical ids (same weight panel) land on the same XCD -> L2 reuse.
__device__ __forceinline__ int xcd_swz(int w0, int nwg) {
  const int q = nwg >> 3, r = nwg & 7;
  const int xcd = w0 & 7, idx = w0 >> 3;
  const int base = (xcd < r) ? xcd * (q + 1) : r * (q + 1) + (xcd - r) * q;
  return base + idx;
}

// ---------------------------------------------------------------------------
// Fused gate+up GEMM over one I-panel: h_panel = silu(x@Wg^T)*(x@Wu^T).
// A = x fp32 staged via global_load_lds (16B-granule XOR swizzle on source),
// converted fp32->fp16 at fragment read. B reg-staged + dequant (r3-proven).
// Tile 128x128x64, 4 waves. Full M (mblocks=64), weights read ONCE.
// ---------------------------------------------------------------------------
__global__ __launch_bounds__(256, 2)
void gateup_kernel(const float* __restrict__ X,
                   const int* __restrict__ Qg, const int* __restrict__ Qu,
                   const float* __restrict__ Sg, const float* __restrict__ Zg,
                   const float* __restrict__ Su, const float* __restrict__ Zu,
                   __half* __restrict__ Hws,
                   int i0, int Iw) {
  constexpr int H = 4096, G = 32;
  const int wg = xcd_swz(blockIdx.x, gridDim.x);
  const int mb = wg & 63;        // mb fastest: all 64 mb of a panel co-resident
  const int nb = wg >> 6;
  const int m0 = mb * 128;
  const int n0g = i0 + nb * 128;  // global I-row of weights
  const int tid = threadIdx.x;
  const int lane = tid & 63;
  const int wave = tid >> 6;
  const int wm = (wave >> 1) * 64, wn = (wave & 1) * 64;
  const int l15 = lane & 15, lq = lane >> 4;
  const int rsw = (l15 & 7) << 3;       // fp16 B read swizzle (elements)

  __shared__ float As32[128][64];       // 32 KB raw fp32 x tile
  __shared__ __half Bgs[128][64];
  __shared__ __half Bus[128][64];

  f32x4 accg[4][4], accu[4][4];
#pragma unroll
  for (int i = 0; i < 4; ++i)
#pragma unroll
    for (int j = 0; j < 4; ++j) {
      accg[i][j] = {0.f, 0.f, 0.f, 0.f};
      accu[i][j] = {0.f, 0.f, 0.f, 0.f};
    }

  // A staging coords (fp32, 16B granules): 8 calls x 256 thr x 16B = 32 KB
  const int ar = tid >> 4;        // row-within-16 (0..15)
  const int aj = tid & 15;        // 16B slot (0..15)
  // B staging coords
  const int brow = tid >> 3;      // 0..31
  const int bcol = (tid & 7) * 8; // element col
  const int bswcol = bcol ^ ((brow & 7) << 3);

  for (int k0 = 0; k0 < H; k0 += 64) {
    __syncthreads();
    // ---- stage A: fp32 DMA, linear dest + inverse-swizzled source ----
#pragma unroll
    for (int c = 0; c < 8; ++c) {
      const int r = c * 16 + ar;
      const float* src = X + (size_t)(m0 + r) * H + k0 + ((aj ^ (r & 7)) << 2);
      float* dst = &As32[0][0] + (size_t)(c * 256 + tid) * 4;
      __builtin_amdgcn_global_load_lds((const __attribute__((address_space(1))) void*)src,
                                       (__attribute__((address_space(3))) void*)dst, 16, 0, 0);
    }
    // ---- stage B: load q, dequant (scales inline), swizzled ds_write ----
    const int gidx = k0 >> 7;
#pragma unroll
    for (int it = 0; it < 4; ++it) {
      const int r = it * 32 + brow;
      const int rg = n0g + r;
      {
        const int* qp = Qg + (size_t)rg * H + (k0 + bcol);
        int4 q0 = *(const int4*)qp, q1 = *(const int4*)(qp + 4);
        *(s16x8*)&Bgs[r][bswcol] = dq_compute(q0, q1, Sg[rg * G + gidx], Zg[rg * G + gidx]);
      }
      {
        const int* qp = Qu + (size_t)rg * H + (k0 + bcol);
        int4 q0 = *(const int4*)qp, q1 = *(const int4*)(qp + 4);
        *(s16x8*)&Bus[r][bswcol] = dq_compute(q0, q1, Su[rg * G + gidx], Zu[rg * G + gidx]);
      }
    }
    __syncthreads();
    // ---- MFMA over BK=64 (two K=32 steps); A converted on read ----
#pragma unroll
    for (int kk = 0; kk < 2; ++kk) {
      f16x8 af[4];
#pragma unroll
      for (int i = 0; i < 4; ++i) {
        const int R = wm + i * 16 + l15;
        const int b0 = kk * 128 + lq * 32;  // byte col of 8 floats
        const char* rowp = (const char*)&As32[R][0];
        f32x4 lo = *(const f32x4*)(rowp + ((b0) ^ ((R & 7) << 4)));
        f32x4 hi = *(const f32x4*)(rowp + ((b0 + 16) ^ ((R & 7) << 4)));
        union { f16x8 v; __half2 h2[4]; } u;
        u.h2[0] = __floats2half2_rn(lo[0], lo[1]);
        u.h2[1] = __floats2half2_rn(lo[2], lo[3]);
        u.h2[2] = __floats2half2_rn(hi[0], hi[1]);
        u.h2[3] = __floats2half2_rn(hi[2], hi[3]);
        af[i] = u.v;
      }
      const int cbase = (kk * 32 + lq * 8) ^ rsw;
#pragma unroll
      for (int j = 0; j < 4; ++j) {
        f16x8 bg = *(const f16x8*)&Bgs[wn + j * 16 + l15][cbase];
        f16x8 bu = *(const f16x8*)&Bus[wn + j * 16 + l15][cbase];
#pragma unroll
        for (int i = 0; i < 4; ++i) {
          accg[i][j] = __builtin_amdgcn_mfma_f32_16x16x32_f16(af[i], bg, accg[i][j], 0, 0, 0);
          accu[i][j] = __builtin_amdgcn_mfma_f32_16x16x32_f16(af[i], bu, accu[i][j], 0, 0, 0);
        }
      }
    }
  }
  // ---- epilogue: h = silu(g)*u -> fp16 panel [8192][Iw] ----
#pragma unroll
  for (int i = 0; i < 4; ++i)
#pragma unroll
    for (int j = 0; j < 4; ++j)
#pragma unroll
      for (int r = 0; r < 4; ++r) {
        const int row = m0 + wm + i * 16 + lq * 4 + r;
        const int col = nb * 128 + wn + j * 16 + l15;  // panel-local col
        float g = accg[i][j][r];
        float u = accu[i][j][r];
        float hv = (g / (1.f + __expf(-g))) * u;
        Hws[(size_t)row * Iw + col] = __float2half(hv);
      }
}

// ---------------------------------------------------------------------------
// Down GEMM K-split: out (+)= h_panel @ Wd[:, i0:i0+Iw]^T.  beta: 0=write 1=acc
// ---------------------------------------------------------------------------
__global__ __launch_bounds__(256, 3)
void down_kernel(const __half* __restrict__ Hws,
                 const int* __restrict__ Qd,
                 const float* __restrict__ Sd, const float* __restrict__ Zd,
                 float* __restrict__ Out,
                 int i0, int Iw, int beta) {
  constexpr int I = 11008, N = 4096, G = 86;
  const int wg = xcd_swz(blockIdx.x, gridDim.x);
  const int mb = wg & 63;
  const int nb = wg >> 6;
  const int m0 = mb * 128, n0 = nb * 128;
  const int tid = threadIdx.x;
  const int lane = tid & 63;
  const int wave = tid >> 6;
  const int wm = (wave >> 1) * 64, wn = (wave & 1) * 64;
  const int l15 = lane & 15, lq = lane >> 4;
  const int rsw = (l15 & 7) << 3;
  const int brow = tid >> 3;
  const int bcol = (tid & 7) * 8;
  const int bswcol = bcol ^ ((brow & 7) << 3);

  __shared__ __half As[128][64];
  __shared__ __half Bs[128][64];

  f32x4 acc[4][4];
#pragma unroll
  for (int i = 0; i < 4; ++i)
#pragma unroll
    for (int j = 0; j < 4; ++j) acc[i][j] = {0.f, 0.f, 0.f, 0.f};

  for (int k0 = 0; k0 < Iw; k0 += 64) {
    __syncthreads();
    // ---- stage A (h panel fp16): DMA, linear dest + swizzled source ----
#pragma unroll
    for (int c = 0; c < 4; ++c) {
      const int r = c * 32 + brow;
      const __half* src = Hws + (size_t)(m0 + r) * Iw + (k0 + bswcol);
      __half* dst = &As[0][0] + (size_t)(c * 256 + tid) * 8;
      __builtin_amdgcn_global_load_lds((const __attribute__((address_space(1))) void*)src,
                                       (__attribute__((address_space(3))) void*)dst, 16, 0, 0);
    }
    // ---- stage B: Wd columns [i0+k0 ..], dequant, swizzled write ----
    const int gidx = (i0 + k0) >> 7;
#pragma unroll
    for (int it = 0; it < 4; ++it) {
      const int r = it * 32 + brow;
      const int rg = n0 + r;
      const int* qp = Qd + (size_t)rg * I + (i0 + k0 + bcol);
      int4 q0 = *(const int4*)qp, q1 = *(const int4*)(qp + 4);
      *(s16x8*)&Bs[r][bswcol] = dq_compute(q0, q1, Sd[rg * G + gidx], Zd[rg * G + gidx]);
    }
    __syncthreads();
#pragma unroll
    for (int kk = 0; kk < 2; ++kk) {
      const int cbase = (kk * 32 + lq * 8) ^ rsw;
      f16x8 af[4];
#pragma unroll
      for (int i = 0; i < 4; ++i)
        af[i] = *(const f16x8*)&As[wm + i * 16 + l15][cbase];
#pragma unroll
      for (int j = 0; j < 4; ++j) {
        f16x8 bf = *(const f16x8*)&Bs[wn + j * 16 + l15][cbase];
#pragma unroll
        for (int i = 0; i < 4; ++i)
          acc[i][j] = __builtin_amdgcn_mfma_f32_16x16x32_f16(af[i], bf, acc[i][j], 0, 0, 0);
      }
    }
  }
#pragma unroll
  for (int i = 0; i < 4; ++i)
#pragma unroll
    for (int j = 0; j < 4; ++j)
#pragma unroll
      for (int r = 0; r < 4; ++r) {
        const int row = m0 + wm + i * 16 + lq * 4 + r;
        const int col = n0 + wn + j * 16 + l15;
        const size_t idx = (size_t)row * N + col;
        if (beta) Out[idx] += acc[i][j][r];
        else      Out[idx] = acc[i][j][r];
      }
}

// ---------------------------------------------------------------------------
extern "C" void kernel_launch(void* const* d_in, const int* in_sizes, int n_in,
                              void* d_out, int out_size, void* d_ws, size_t ws_size,
                              hipStream_t stream) {
  const float* x  = (const float*)d_in[0];
  const int* qg   = (const int*)d_in[1];
  const int* qu   = (const int*)d_in[2];
  const int* qd   = (const int*)d_in[3];
  const float* sg = (const float*)d_in[4];
  const float* zg = (const float*)d_in[5];
  const float* su = (const float*)d_in[6];
  const float* zu = (const float*)d_in[7];
  const float* sd = (const float*)d_in[8];
  const float* zd = (const float*)d_in[9];
  float* out = (float*)d_out;

  const int M = 8192, NBTOT = 86;  // I = 86*128

  // I-chunking: h panel [M][nbB*128] fp16 must fit in ws.
  const size_t panel_bytes = (size_t)M * 128 * 2;  // per 128-col block: 2 MB
  int maxnb = (int)(ws_size / panel_bytes);
  if (maxnb > NBTOT) maxnb = NBTOT;
  if (maxnb < 1) maxnb = 1;
  const int nch = (NBTOT + maxnb - 1) / maxnb;
  const int base = NBTOT / nch, rem = NBTOT % nch;

  __half* hpanel = (__half*)d_ws;

  int i0blk = 0;
  for (int c = 0; c < nch; ++c) {
    const int nbB = base + (c < rem ? 1 : 0);
    const int i0 = i0blk * 128;
    const int Iw = nbB * 128;
    gateup_kernel<<<nbB * 64, 256, 0, stream>>>(
        x, qg, qu, sg, zg, su, zu, hpanel, i0, Iw);
    down_kernel<<<32 * 64, 256, 0, stream>>>(
        hpanel, qd, sd, zd, out, i0, Iw, c == 0 ? 0 : 1);
    i0blk += nbB;
  }
}